// Round 1
// baseline (3119.513 us; speedup 1.0000x reference)
//
#include <hip/hip_runtime.h>
#include <math.h>

// ---------------------------------------------------------------------------
// 3-layer GCN: h = relu(GCNConv(x)) x2, out = log_softmax(GCNConv(h))
// GCNConv: h = x@W; deg from dst(+self); out[d] += h[s]*dis[s]*dis[d]; +bias
// N=100000, E=1200000, F: 128 -> 64 -> 64 -> 40
// ---------------------------------------------------------------------------

__global__ void k_init_deg(float* __restrict__ deg, int n) {
    int i = blockIdx.x * blockDim.x + threadIdx.x;
    if (i < n) deg[i] = 1.0f;  // self-loop
}

__global__ void k_count_deg(const int* __restrict__ dst, float* __restrict__ deg, int E) {
    int i = blockIdx.x * blockDim.x + threadIdx.x;
    if (i < E) atomicAdd(&deg[dst[i]], 1.0f);
}

__global__ void k_rsqrt(float* __restrict__ deg, int n) {
    int i = blockIdx.x * blockDim.x + threadIdx.x;
    if (i < n) deg[i] = rsqrtf(deg[i]);
}

// Row-per-wave GEMM: H[N,M] = X[N,K] @ W[K,M].  4 rows per 256-thread block.
// X row staged in LDS; W (<=32KB) is L1-resident; lane j computes column j.
template<int K, int M>
__global__ void k_gemm(const float* __restrict__ X, const float* __restrict__ W,
                       float* __restrict__ H, int N) {
    __shared__ float xs[4][K];
    const int grp  = threadIdx.x >> 6;
    const int lane = threadIdx.x & 63;
    const int row  = blockIdx.x * 4 + grp;
    for (int k = lane; k < K; k += 64)
        xs[grp][k] = (row < N) ? X[row * K + k] : 0.0f;
    __syncthreads();
    if (row < N && lane < M) {
        float acc = 0.0f;
#pragma unroll
        for (int k = 0; k < K; ++k)
            acc = fmaf(xs[grp][k], W[k * M + lane], acc);
        H[row * M + lane] = acc;
    }
}

// A[i,f] = H[i,f] * dis[i]^2   (self-loop contribution; also zero-inits A)
template<int F>
__global__ void k_self_init(const float* __restrict__ H, const float* __restrict__ dis,
                            float* __restrict__ A, int N) {
    int tid = blockIdx.x * blockDim.x + threadIdx.x;
    if (tid >= N * F) return;
    int node = tid / F;
    float dd = dis[node];
    A[tid] = H[tid] * dd * dd;
}

// Per edge: A[dst] += H[src] * dis[src]*dis[dst].  One thread = 4 features.
template<int F>
__global__ void k_edge_scatter(const float* __restrict__ H, const float* __restrict__ dis,
                               const int* __restrict__ src, const int* __restrict__ dst,
                               float* __restrict__ A, int E) {
    constexpr int PG = F / 4;
    int tid = blockIdx.x * blockDim.x + threadIdx.x;
    if (tid >= E * PG) return;
    int e = tid / PG;
    int g = tid % PG;
    int s = src[e];
    int d = dst[e];
    float nrm = dis[s] * dis[d];
    const float4 v = *(const float4*)(H + s * F + g * 4);
    float* out = A + d * F + g * 4;
    atomicAdd(out + 0, v.x * nrm);
    atomicAdd(out + 1, v.y * nrm);
    atomicAdd(out + 2, v.z * nrm);
    atomicAdd(out + 3, v.w * nrm);
}

// A = relu(A + b)
template<int F>
__global__ void k_bias_relu(float* __restrict__ A, const float* __restrict__ b, int N) {
    int tid = blockIdx.x * blockDim.x + threadIdx.x;
    if (tid >= N * F) return;
    int f = tid % F;
    A[tid] = fmaxf(A[tid] + b[f], 0.0f);
}

// out[node,:] = log_softmax(out[node,:] + b)  over F_OUT=40. One wave per node.
__global__ void k_bias_logsoftmax40(float* __restrict__ out, const float* __restrict__ b, int N) {
    const int wave = threadIdx.x >> 6;
    const int lane = threadIdx.x & 63;
    const int node = blockIdx.x * (blockDim.x >> 6) + wave;
    if (node >= N) return;
    float v = -INFINITY;
    if (lane < 40) v = out[node * 40 + lane] + b[lane];
    float m = v;
#pragma unroll
    for (int o = 32; o > 0; o >>= 1) m = fmaxf(m, __shfl_xor(m, o, 64));
    float ex = (lane < 40) ? expf(v - m) : 0.0f;
    float ssum = ex;
#pragma unroll
    for (int o = 32; o > 0; o >>= 1) ssum += __shfl_xor(ssum, o, 64);
    if (lane < 40) out[node * 40 + lane] = v - m - logf(ssum);
}

static inline int cdiv(long a, int b) { return (int)((a + b - 1) / b); }

extern "C" void kernel_launch(void* const* d_in, const int* in_sizes, int n_in,
                              void* d_out, int out_size, void* d_ws, size_t ws_size,
                              hipStream_t stream) {
    const float* x  = (const float*)d_in[0];
    const int*   ei = (const int*)d_in[1];
    const float* W1 = (const float*)d_in[2];
    const float* b1 = (const float*)d_in[3];
    const float* W2 = (const float*)d_in[4];
    const float* b2 = (const float*)d_in[5];
    const float* W3 = (const float*)d_in[6];
    const float* b3 = (const float*)d_in[7];
    float* out = (float*)d_out;

    const int N = in_sizes[0] / 128;
    const int E = in_sizes[1] / 2;
    const int* src = ei;
    const int* dst = ei + E;

    float* wsf  = (float*)d_ws;
    float* dis  = wsf;                  // N floats
    float* hbuf = wsf + N;              // N*64 floats
    float* abuf = hbuf + (size_t)N * 64;// N*64 floats

    const int B = 256;

    // degree -> rsqrt
    k_init_deg<<<cdiv(N, B), B, 0, stream>>>(dis, N);
    k_count_deg<<<cdiv(E, B), B, 0, stream>>>(dst, dis, E);
    k_rsqrt<<<cdiv(N, B), B, 0, stream>>>(dis, N);

    // ---- layer 1: x[N,128] @ W1 -> 64, aggregate, relu ----
    k_gemm<128, 64><<<cdiv(N, 4), B, 0, stream>>>(x, W1, hbuf, N);
    k_self_init<64><<<cdiv((long)N * 64, B), B, 0, stream>>>(hbuf, dis, abuf, N);
    k_edge_scatter<64><<<cdiv((long)E * 16, B), B, 0, stream>>>(hbuf, dis, src, dst, abuf, E);
    k_bias_relu<64><<<cdiv((long)N * 64, B), B, 0, stream>>>(abuf, b1, N);

    // ---- layer 2: abuf[N,64] @ W2 -> 64, aggregate, relu ----
    k_gemm<64, 64><<<cdiv(N, 4), B, 0, stream>>>(abuf, W2, hbuf, N);
    k_self_init<64><<<cdiv((long)N * 64, B), B, 0, stream>>>(hbuf, dis, abuf, N);
    k_edge_scatter<64><<<cdiv((long)E * 16, B), B, 0, stream>>>(hbuf, dis, src, dst, abuf, E);
    k_bias_relu<64><<<cdiv((long)N * 64, B), B, 0, stream>>>(abuf, b2, N);

    // ---- layer 3: abuf[N,64] @ W3 -> 40, aggregate into d_out ----
    k_gemm<64, 40><<<cdiv(N, 4), B, 0, stream>>>(abuf, W3, hbuf, N);
    k_self_init<40><<<cdiv((long)N * 40, B), B, 0, stream>>>(hbuf, dis, out, N);
    k_edge_scatter<40><<<cdiv((long)E * 10, B), B, 0, stream>>>(hbuf, dis, src, dst, out, E);

    // ---- bias + log_softmax (in-place on d_out) ----
    k_bias_logsoftmax40<<<cdiv(N, 4), B, 0, stream>>>(out, b3, N);
}

// Round 2
// 772.600 us; speedup vs baseline: 4.0377x; 4.0377x over previous
//
#include <hip/hip_runtime.h>
#include <math.h>

// ---------------------------------------------------------------------------
// 3-layer GCN, CSR-gather formulation (no fp32 atomics in hot path).
// Per launch: build dst-CSR (hist -> scan -> scatter (src,nrm) pairs),
// then per layer: GEMM -> wave-per-node gather-aggregate (fused self-loop,
// bias, relu / log_softmax).
// N=100000, E=1200000, F: 128 -> 64 -> 64 -> 40
// ---------------------------------------------------------------------------

static inline int cdiv(long a, int b) { return (int)((a + b - 1) / b); }

__global__ void k_zero_i32(int* __restrict__ p, int n) {
    int i = blockIdx.x * blockDim.x + threadIdx.x;
    if (i < n) p[i] = 0;
}

__global__ void k_hist(const int* __restrict__ dst, int* __restrict__ cnt, int E) {
    int i = blockIdx.x * blockDim.x + threadIdx.x;
    if (i < E) atomicAdd(&cnt[dst[i]], 1);
}

__global__ void k_dis(const int* __restrict__ cnt, float* __restrict__ dis, int n) {
    int i = blockIdx.x * blockDim.x + threadIdx.x;
    if (i < n) dis[i] = rsqrtf(1.0f + (float)cnt[i]);  // +1 self-loop
}

// ---- 3-step exclusive scan of cnt[0..n) into rp[0..n], rp[n]=E ----
#define SCAN_B 1024
__global__ void k_scan1(const int* __restrict__ cnt, int* __restrict__ rp,
                        int* __restrict__ bsum, int n) {
    __shared__ int sm[SCAN_B];
    const int tid = threadIdx.x;
    const int gid = blockIdx.x * SCAN_B + tid;
    int v = (gid < n) ? cnt[gid] : 0;
    sm[tid] = v;
    __syncthreads();
    for (int off = 1; off < SCAN_B; off <<= 1) {
        int t = (tid >= off) ? sm[tid - off] : 0;
        __syncthreads();
        sm[tid] += t;
        __syncthreads();
    }
    if (gid < n) rp[gid] = sm[tid] - v;           // exclusive
    if (tid == SCAN_B - 1) bsum[blockIdx.x] = sm[tid];
}

__global__ void k_scan2(int* __restrict__ bsum, int nb) {
    __shared__ int sm[SCAN_B];
    const int tid = threadIdx.x;
    int v = (tid < nb) ? bsum[tid] : 0;
    sm[tid] = v;
    __syncthreads();
    for (int off = 1; off < SCAN_B; off <<= 1) {
        int t = (tid >= off) ? sm[tid - off] : 0;
        __syncthreads();
        sm[tid] += t;
        __syncthreads();
    }
    if (tid < nb) bsum[tid] = sm[tid] - v;        // exclusive
}

__global__ void k_scan3(int* __restrict__ rp, const int* __restrict__ bsum, int n, int E) {
    const int gid = blockIdx.x * SCAN_B + threadIdx.x;
    if (gid < n) rp[gid] += bsum[gid / SCAN_B];
    if (gid == n) rp[n] = E;
}

// scatter (src, nrm) into CSR slots
__global__ void k_build(const int* __restrict__ src, const int* __restrict__ dst,
                        const float* __restrict__ dis, const int* __restrict__ rp,
                        int* __restrict__ fill, int2* __restrict__ edata, int E) {
    int e = blockIdx.x * blockDim.x + threadIdx.x;
    if (e >= E) return;
    int d = dst[e];
    int s = src[e];
    int pos = atomicAdd(&fill[d], 1);
    float nrm = dis[s] * dis[d];
    edata[rp[d] + pos] = make_int2(s, __float_as_int(nrm));
}

// Row-per-wave GEMM: H[N,M] = X[N,K] @ W[K,M]; 4 rows / 256-thread block.
template<int K, int M>
__global__ void k_gemm(const float* __restrict__ X, const float* __restrict__ W,
                       float* __restrict__ H, int N) {
    __shared__ float xs[4][K];
    const int grp  = threadIdx.x >> 6;
    const int lane = threadIdx.x & 63;
    const int row  = blockIdx.x * 4 + grp;
    for (int k = lane; k < K; k += 64)
        xs[grp][k] = (row < N) ? X[row * K + k] : 0.0f;
    __syncthreads();
    if (row < N && lane < M) {
        float acc = 0.0f;
#pragma unroll
        for (int k = 0; k < K; ++k)
            acc = fmaf(xs[grp][k], W[k * M + lane], acc);
        H[row * M + lane] = acc;
    }
}

// Wave-per-node aggregation, F=64: lane=feature.
// A[node] = relu( sum_in-edges H[src]*nrm + H[node]*dis^2 + bias )
__global__ void k_aggregate64(const float* __restrict__ H, const float* __restrict__ dis,
                              const int* __restrict__ rp, const int2* __restrict__ edata,
                              const float* __restrict__ bias, float* __restrict__ A, int N) {
    const int wave = threadIdx.x >> 6;
    const int lane = threadIdx.x & 63;
    const int node = blockIdx.x * (blockDim.x >> 6) + wave;
    if (node >= N) return;
    const float dd = dis[node];
    float acc = H[(size_t)node * 64 + lane] * dd * dd;
    const int e1 = rp[node + 1];
    for (int e = rp[node]; e < e1; ++e) {
        int2 p = edata[e];
        acc = fmaf(H[(size_t)p.x * 64 + lane], __int_as_float(p.y), acc);
    }
    A[(size_t)node * 64 + lane] = fmaxf(acc + bias[lane], 0.0f);
}

// Final layer: F=40 aggregation fused with bias + log_softmax.
__global__ void k_aggregate40_lsm(const float* __restrict__ H, const float* __restrict__ dis,
                                  const int* __restrict__ rp, const int2* __restrict__ edata,
                                  const float* __restrict__ bias, float* __restrict__ out, int N) {
    const int wave = threadIdx.x >> 6;
    const int lane = threadIdx.x & 63;
    const int node = blockIdx.x * (blockDim.x >> 6) + wave;
    if (node >= N) return;
    const float dd = dis[node];
    float acc = 0.0f;
    if (lane < 40) acc = H[(size_t)node * 40 + lane] * dd * dd;
    const int e1 = rp[node + 1];
    for (int e = rp[node]; e < e1; ++e) {
        int2 p = edata[e];
        if (lane < 40) acc = fmaf(H[(size_t)p.x * 40 + lane], __int_as_float(p.y), acc);
    }
    float v = (lane < 40) ? acc + bias[lane] : -INFINITY;
    float m = v;
#pragma unroll
    for (int o = 32; o > 0; o >>= 1) m = fmaxf(m, __shfl_xor(m, o, 64));
    float ex = (lane < 40) ? expf(v - m) : 0.0f;
    float ssum = ex;
#pragma unroll
    for (int o = 32; o > 0; o >>= 1) ssum += __shfl_xor(ssum, o, 64);
    if (lane < 40) out[(size_t)node * 40 + lane] = v - m - logf(ssum);
}

extern "C" void kernel_launch(void* const* d_in, const int* in_sizes, int n_in,
                              void* d_out, int out_size, void* d_ws, size_t ws_size,
                              hipStream_t stream) {
    const float* x  = (const float*)d_in[0];
    const int*   ei = (const int*)d_in[1];
    const float* W1 = (const float*)d_in[2];
    const float* b1 = (const float*)d_in[3];
    const float* W2 = (const float*)d_in[4];
    const float* b2 = (const float*)d_in[5];
    const float* W3 = (const float*)d_in[6];
    const float* b3 = (const float*)d_in[7];
    float* out = (float*)d_out;

    const int N = in_sizes[0] / 128;
    const int E = in_sizes[1] / 2;
    const int* src = ei;
    const int* dst = ei + E;

    // ---- workspace layout (8B-aligned first) ----
    char* ws = (char*)d_ws;
    int2*  edata = (int2*)ws;                 ws += (size_t)E * sizeof(int2);       // 9.6 MB
    float* hbuf  = (float*)ws;                ws += (size_t)N * 64 * sizeof(float); // 25.6 MB
    float* abuf  = (float*)ws;                ws += (size_t)N * 64 * sizeof(float); // 25.6 MB
    int*   cnt   = (int*)ws;                  ws += (size_t)N * sizeof(int);
    int*   fill  = (int*)ws;                  ws += (size_t)N * sizeof(int);
    int*   rp    = (int*)ws;                  ws += (size_t)(N + 1) * sizeof(int);
    int*   bsum  = (int*)ws;                  ws += (size_t)SCAN_B * sizeof(int);
    float* dis   = (float*)ws;                ws += (size_t)N * sizeof(float);

    const int B = 256;
    const int nb = cdiv(N, SCAN_B);

    // ---- CSR build ----
    k_zero_i32<<<cdiv(2 * N, B), B, 0, stream>>>(cnt, 2 * N);  // cnt + fill adjacent
    k_hist<<<cdiv(E, B), B, 0, stream>>>(dst, cnt, E);
    k_dis<<<cdiv(N, B), B, 0, stream>>>(cnt, dis, N);
    k_scan1<<<nb, SCAN_B, 0, stream>>>(cnt, rp, bsum, N);
    k_scan2<<<1, SCAN_B, 0, stream>>>(bsum, nb);
    k_scan3<<<cdiv(N + 1, SCAN_B), SCAN_B, 0, stream>>>(rp, bsum, N, E);
    k_build<<<cdiv(E, B), B, 0, stream>>>(src, dst, dis, rp, fill, edata, E);

    // ---- layer 1: x[N,128] @ W1 -> hbuf[N,64]; aggregate+relu -> abuf ----
    k_gemm<128, 64><<<cdiv(N, 4), B, 0, stream>>>(x, W1, hbuf, N);
    k_aggregate64<<<cdiv(N, 4), B, 0, stream>>>(hbuf, dis, rp, edata, b1, abuf, N);

    // ---- layer 2 ----
    k_gemm<64, 64><<<cdiv(N, 4), B, 0, stream>>>(abuf, W2, hbuf, N);
    k_aggregate64<<<cdiv(N, 4), B, 0, stream>>>(hbuf, dis, rp, edata, b2, abuf, N);

    // ---- layer 3 + log_softmax ----
    k_gemm<64, 40><<<cdiv(N, 4), B, 0, stream>>>(abuf, W3, hbuf, N);
    k_aggregate40_lsm<<<cdiv(N, 4), B, 0, stream>>>(hbuf, dis, rp, edata, b3, out, N);
}

// Round 3
// 618.873 us; speedup vs baseline: 5.0406x; 1.2484x over previous
//
#include <hip/hip_runtime.h>
#include <math.h>

// ---------------------------------------------------------------------------
// 3-layer GCN, CSR-gather formulation, unroll-4 MLP in aggregation.
// Layer 3 reordered: A(h2 W3) == (A h2) W3  ->  aligned F=64 aggregate +
// tiny fused GEMM64x40 + bias + log_softmax.
// N=100000, E=1200000, F: 128 -> 64 -> 64 -> 40
// ---------------------------------------------------------------------------

static inline int cdiv(long a, int b) { return (int)((a + b - 1) / b); }

__global__ void k_zero_i32(int* __restrict__ p, int n) {
    int i = blockIdx.x * blockDim.x + threadIdx.x;
    if (i < n) p[i] = 0;
}

__global__ void k_hist(const int* __restrict__ dst, int* __restrict__ cnt, int E) {
    int i = blockIdx.x * blockDim.x + threadIdx.x;
    if (i < E) atomicAdd(&cnt[dst[i]], 1);
}

__global__ void k_dis(const int* __restrict__ cnt, float* __restrict__ dis, int n) {
    int i = blockIdx.x * blockDim.x + threadIdx.x;
    if (i < n) dis[i] = rsqrtf(1.0f + (float)cnt[i]);  // +1 self-loop
}

// ---- 3-step exclusive scan of cnt[0..n) into rp[0..n], rp[n]=E ----
#define SCAN_B 1024
__global__ void k_scan1(const int* __restrict__ cnt, int* __restrict__ rp,
                        int* __restrict__ bsum, int n) {
    __shared__ int sm[SCAN_B];
    const int tid = threadIdx.x;
    const int gid = blockIdx.x * SCAN_B + tid;
    int v = (gid < n) ? cnt[gid] : 0;
    sm[tid] = v;
    __syncthreads();
    for (int off = 1; off < SCAN_B; off <<= 1) {
        int t = (tid >= off) ? sm[tid - off] : 0;
        __syncthreads();
        sm[tid] += t;
        __syncthreads();
    }
    if (gid < n) rp[gid] = sm[tid] - v;           // exclusive
    if (tid == SCAN_B - 1) bsum[blockIdx.x] = sm[tid];
}

__global__ void k_scan2(int* __restrict__ bsum, int nb) {
    __shared__ int sm[SCAN_B];
    const int tid = threadIdx.x;
    int v = (tid < nb) ? bsum[tid] : 0;
    sm[tid] = v;
    __syncthreads();
    for (int off = 1; off < SCAN_B; off <<= 1) {
        int t = (tid >= off) ? sm[tid - off] : 0;
        __syncthreads();
        sm[tid] += t;
        __syncthreads();
    }
    if (tid < nb) bsum[tid] = sm[tid] - v;        // exclusive
}

__global__ void k_scan3(int* __restrict__ rp, const int* __restrict__ bsum, int n, int E) {
    const int gid = blockIdx.x * SCAN_B + threadIdx.x;
    if (gid < n) rp[gid] += bsum[gid / SCAN_B];
    if (gid == n) rp[n] = E;
}

// scatter (src, nrm) into CSR slots
__global__ void k_build(const int* __restrict__ src, const int* __restrict__ dst,
                        const float* __restrict__ dis, const int* __restrict__ rp,
                        int* __restrict__ fill, int2* __restrict__ edata, int E) {
    int e = blockIdx.x * blockDim.x + threadIdx.x;
    if (e >= E) return;
    int d = dst[e];
    int s = src[e];
    int pos = atomicAdd(&fill[d], 1);
    float nrm = dis[s] * dis[d];
    edata[rp[d] + pos] = make_int2(s, __float_as_int(nrm));
}

// Row-per-wave GEMM: H[N,M] = X[N,K] @ W[K,M]; 4 rows / 256-thread block.
template<int K, int M>
__global__ void k_gemm(const float* __restrict__ X, const float* __restrict__ W,
                       float* __restrict__ H, int N) {
    __shared__ float xs[4][K];
    const int grp  = threadIdx.x >> 6;
    const int lane = threadIdx.x & 63;
    const int row  = blockIdx.x * 4 + grp;
    for (int k = lane; k < K; k += 64)
        xs[grp][k] = (row < N) ? X[row * K + k] : 0.0f;
    __syncthreads();
    if (row < N && lane < M) {
        float acc = 0.0f;
#pragma unroll
        for (int k = 0; k < K; ++k)
            acc = fmaf(xs[grp][k], W[k * M + lane], acc);
        H[row * M + lane] = acc;
    }
}

// Wave-per-node aggregation, F=64, unroll-4 for memory-level parallelism.
// A[node] = post( sum_in-edges H[src]*nrm + H[node]*dis^2 (+ bias) )
template<bool BIAS_RELU>
__global__ void k_agg64(const float* __restrict__ H, const float* __restrict__ dis,
                        const int* __restrict__ rp, const int2* __restrict__ edata,
                        const float* __restrict__ bias, float* __restrict__ A, int N) {
    const int wave = threadIdx.x >> 6;
    const int lane = threadIdx.x & 63;
    const int node = blockIdx.x * (blockDim.x >> 6) + wave;
    if (node >= N) return;
    const float dd = dis[node];
    float a0 = H[(size_t)node * 64 + lane] * dd * dd;  // self-loop
    float a1 = 0.f, a2 = 0.f, a3 = 0.f;
    int e = rp[node];
    const int e1 = rp[node + 1];
    for (; e + 4 <= e1; e += 4) {
        int2 p0 = edata[e + 0];
        int2 p1 = edata[e + 1];
        int2 p2 = edata[e + 2];
        int2 p3 = edata[e + 3];
        float h0 = H[(size_t)p0.x * 64 + lane];
        float h1 = H[(size_t)p1.x * 64 + lane];
        float h2 = H[(size_t)p2.x * 64 + lane];
        float h3 = H[(size_t)p3.x * 64 + lane];
        a0 = fmaf(h0, __int_as_float(p0.y), a0);
        a1 = fmaf(h1, __int_as_float(p1.y), a1);
        a2 = fmaf(h2, __int_as_float(p2.y), a2);
        a3 = fmaf(h3, __int_as_float(p3.y), a3);
    }
    for (; e < e1; ++e) {
        int2 p = edata[e];
        a0 = fmaf(H[(size_t)p.x * 64 + lane], __int_as_float(p.y), a0);
    }
    float acc = (a0 + a1) + (a2 + a3);
    if (BIAS_RELU) acc = fmaxf(acc + bias[lane], 0.0f);
    A[(size_t)node * 64 + lane] = acc;
}

// Final tiny GEMM: out[node,:40] = log_softmax( X[node,:64] @ W3[64,40] + b3 ).
// One wave per node; X-row held one value per lane, broadcast via shuffle.
__global__ void k_gemm40_lsm(const float* __restrict__ X, const float* __restrict__ W,
                             const float* __restrict__ bias, float* __restrict__ out, int N) {
    const int wave = threadIdx.x >> 6;
    const int lane = threadIdx.x & 63;
    const int node = blockIdx.x * (blockDim.x >> 6) + wave;
    if (node >= N) return;
    const float xv = X[(size_t)node * 64 + lane];
    const int cl = (lane < 40) ? lane : 0;   // clamp to keep W reads in-bounds
    float acc = 0.0f;
#pragma unroll
    for (int k = 0; k < 64; ++k) {
        float xk = __shfl(xv, k, 64);
        acc = fmaf(xk, W[k * 40 + cl], acc);
    }
    float v = (lane < 40) ? acc + bias[cl] : -INFINITY;
    float m = v;
#pragma unroll
    for (int o = 32; o > 0; o >>= 1) m = fmaxf(m, __shfl_xor(m, o, 64));
    float ex = (lane < 40) ? expf(v - m) : 0.0f;
    float ssum = ex;
#pragma unroll
    for (int o = 32; o > 0; o >>= 1) ssum += __shfl_xor(ssum, o, 64);
    if (lane < 40) out[(size_t)node * 40 + lane] = v - m - logf(ssum);
}

extern "C" void kernel_launch(void* const* d_in, const int* in_sizes, int n_in,
                              void* d_out, int out_size, void* d_ws, size_t ws_size,
                              hipStream_t stream) {
    const float* x  = (const float*)d_in[0];
    const int*   ei = (const int*)d_in[1];
    const float* W1 = (const float*)d_in[2];
    const float* b1 = (const float*)d_in[3];
    const float* W2 = (const float*)d_in[4];
    const float* b2 = (const float*)d_in[5];
    const float* W3 = (const float*)d_in[6];
    const float* b3 = (const float*)d_in[7];
    float* out = (float*)d_out;

    const int N = in_sizes[0] / 128;
    const int E = in_sizes[1] / 2;
    const int* src = ei;
    const int* dst = ei + E;

    // ---- workspace layout (8B-aligned first) ----
    char* ws = (char*)d_ws;
    int2*  edata = (int2*)ws;                 ws += (size_t)E * sizeof(int2);       // 9.6 MB
    float* hbuf  = (float*)ws;                ws += (size_t)N * 64 * sizeof(float); // 25.6 MB
    float* abuf  = (float*)ws;                ws += (size_t)N * 64 * sizeof(float); // 25.6 MB
    int*   cnt   = (int*)ws;                  ws += (size_t)N * sizeof(int);
    int*   fill  = (int*)ws;                  ws += (size_t)N * sizeof(int);
    int*   rp    = (int*)ws;                  ws += (size_t)(N + 1) * sizeof(int);
    int*   bsum  = (int*)ws;                  ws += (size_t)SCAN_B * sizeof(int);
    float* dis   = (float*)ws;                ws += (size_t)N * sizeof(float);

    const int B = 256;
    const int nb = cdiv(N, SCAN_B);

    // ---- CSR build ----
    k_zero_i32<<<cdiv(2 * N, B), B, 0, stream>>>(cnt, 2 * N);  // cnt + fill adjacent
    k_hist<<<cdiv(E, B), B, 0, stream>>>(dst, cnt, E);
    k_dis<<<cdiv(N, B), B, 0, stream>>>(cnt, dis, N);
    k_scan1<<<nb, SCAN_B, 0, stream>>>(cnt, rp, bsum, N);
    k_scan2<<<1, SCAN_B, 0, stream>>>(bsum, nb);
    k_scan3<<<cdiv(N + 1, SCAN_B), SCAN_B, 0, stream>>>(rp, bsum, N, E);
    k_build<<<cdiv(E, B), B, 0, stream>>>(src, dst, dis, rp, fill, edata, E);

    // ---- layer 1: x[N,128] @ W1 -> hbuf; aggregate+bias+relu -> abuf ----
    k_gemm<128, 64><<<cdiv(N, 4), B, 0, stream>>>(x, W1, hbuf, N);
    k_agg64<true><<<cdiv(N, 4), B, 0, stream>>>(hbuf, dis, rp, edata, b1, abuf, N);

    // ---- layer 2 ----
    k_gemm<64, 64><<<cdiv(N, 4), B, 0, stream>>>(abuf, W2, hbuf, N);
    k_agg64<true><<<cdiv(N, 4), B, 0, stream>>>(hbuf, dis, rp, edata, b2, abuf, N);

    // ---- layer 3 reordered: (A h2) W3 + b3 -> log_softmax ----
    k_agg64<false><<<cdiv(N, 4), B, 0, stream>>>(abuf, dis, rp, edata, nullptr, hbuf, N);
    k_gemm40_lsm<<<cdiv(N, 4), B, 0, stream>>>(hbuf, W3, b3, out, N);
}